// Round 1
// baseline (310.963 us; speedup 1.0000x reference)
//
#include <hip/hip_runtime.h>

// ---------------------------------------------------------------------------
// CESLayer: out[b,o] = cos(x@angle^T + bias) * exp(x@log|w|^T)
// B=262144, I=O=128. Memory-bound target ~42.5us (268MB @ 6.3TB/s).
// Strategy: bf16 hi/lo split MFMA (3-term) for fp32-grade dot products,
// weights resident in VGPRs, x streamed via LDS, fused transcendental epilogue.
// ---------------------------------------------------------------------------

typedef __attribute__((ext_vector_type(8))) short bf16x8;   // 8 bf16 = 4 VGPRs
typedef __attribute__((ext_vector_type(4))) float f32x4;
typedef __attribute__((ext_vector_type(4))) unsigned short u16x4;

#define MFMA(a, b, c) __builtin_amdgcn_mfma_f32_16x16x32_bf16((a), (b), (c), 0, 0, 0)

__device__ __forceinline__ unsigned short f2bf_rne(float f) {
    unsigned u = __float_as_uint(f);
    unsigned r = u + 0x7FFFu + ((u >> 16) & 1u);
    return (unsigned short)(r >> 16);
}

// Split fp32 -> bf16 hi + bf16 lo (residual). hi+lo reconstructs ~18 mantissa bits.
__device__ __forceinline__ void bf16_split(float f, unsigned short& hi, unsigned short& lo) {
    hi = f2bf_rne(f);
    float hif = __uint_as_float((unsigned)hi << 16);
    lo = f2bf_rne(f - hif);
}

// ---------------------------------------------------------------------------
// Prep: from w_real/w_imag [128x128] compute angle=atan2, logmag=0.5*log(r2),
// split each into bf16 hi/lo. Layout in ws (ushort):
//   [0..16384)       angle_hi   [o*128+i]
//   [16384..32768)   angle_lo
//   [32768..49152)   logmag_hi
//   [49152..65536)   logmag_lo
// ---------------------------------------------------------------------------
__global__ void ces_prep(const float* __restrict__ wr, const float* __restrict__ wi,
                         unsigned short* __restrict__ wsplit) {
    int idx = blockIdx.x * 256 + threadIdx.x;   // 0..16383
    float a = wr[idx], b = wi[idx];
    float r2 = a * a + b * b;
    float ang = atan2f(b, a);
    float lg = 0.5f * logf(r2);
    unsigned short ah, al, gh, gl;
    bf16_split(ang, ah, al);
    bf16_split(lg, gh, gl);
    wsplit[idx]         = ah;
    wsplit[16384 + idx] = al;
    wsplit[32768 + idx] = gh;
    wsplit[49152 + idx] = gl;
}

// ---------------------------------------------------------------------------
// Main kernel. Workgroup = 256 threads = 4 waves. Wave w owns O-cols
// [w*32, w*32+32) as 2 n-tiles of 16. Weight fragments live in VGPRs for the
// whole kernel. Grid-stride over 64-row chunks of B staged through LDS.
// MFMA 16x16x32 bf16: A frag lane layout m=lane&15, k=quad*8+j;
//                     C/D: col=lane&15, row=quad*4+reg  (guide §3, m89/m120).
// ---------------------------------------------------------------------------
#define BM   64
#define LDSP 136   // 128 + 8 pad: row stride 272B -> 4-bank rotation, ~2-way max

__global__ __launch_bounds__(256, 2) void ces_main(
        const float* __restrict__ x,
        const unsigned short* __restrict__ wsplit,
        const float* __restrict__ bias,
        float* __restrict__ out,
        int nchunks) {
    __shared__ unsigned short sxh[BM * LDSP];
    __shared__ unsigned short sxl[BM * LDSP];

    const int tid  = threadIdx.x;
    const int wave = tid >> 6;
    const int lane = tid & 63;
    const int quad = lane >> 4;
    const int l16  = lane & 15;
    const int n0   = wave * 32;

    // ---- weight fragments into registers (once per block) ----
    // B-operand layout: lane holds w[o = ntile_base + (lane&15)][ks*32 + quad*8 + j]
    bf16x8 wfa_h[2][4], wfa_l[2][4], wfg_h[2][4], wfg_l[2][4];
#pragma unroll
    for (int nt = 0; nt < 2; ++nt) {
        int o = n0 + nt * 16 + l16;
#pragma unroll
        for (int ks = 0; ks < 4; ++ks) {
            int off = o * 128 + ks * 32 + quad * 8;
            wfa_h[nt][ks] = *(const bf16x8*)(wsplit + off);
            wfa_l[nt][ks] = *(const bf16x8*)(wsplit + 16384 + off);
            wfg_h[nt][ks] = *(const bf16x8*)(wsplit + 32768 + off);
            wfg_l[nt][ks] = *(const bf16x8*)(wsplit + 49152 + off);
        }
    }
    float bias_v[2];
    bias_v[0] = bias[n0 + l16];
    bias_v[1] = bias[n0 + 16 + l16];

    for (int chunk = blockIdx.x; chunk < nchunks; chunk += gridDim.x) {
        const int R0 = chunk * BM;

        // ---- stage x[R0:R0+64][0:128] -> LDS as bf16 hi/lo ----
        __syncthreads();   // previous chunk's LDS readers done
        const float* xp = x + (size_t)R0 * 128;
#pragma unroll
        for (int it = 0; it < 8; ++it) {
            int f   = tid + it * 256;      // float4 index, 0..2047
            int row = f >> 5;
            int c4  = (f & 31) * 4;
            float4 v = *(const float4*)(xp + row * 128 + c4);
            u16x4 hv, lv;
            bf16_split(v.x, ((unsigned short*)&hv)[0], ((unsigned short*)&lv)[0]);
            bf16_split(v.y, ((unsigned short*)&hv)[1], ((unsigned short*)&lv)[1]);
            bf16_split(v.z, ((unsigned short*)&hv)[2], ((unsigned short*)&lv)[2]);
            bf16_split(v.w, ((unsigned short*)&hv)[3], ((unsigned short*)&lv)[3]);
            *(u16x4*)(&sxh[row * LDSP + c4]) = hv;
            *(u16x4*)(&sxl[row * LDSP + c4]) = lv;
        }
        __syncthreads();

        // ---- MFMA: 4 m-tiles x 2 n-tiles, K=128 in 4 steps of 32 ----
        f32x4 accY[4][2], accG[4][2];
#pragma unroll
        for (int m = 0; m < 4; ++m)
#pragma unroll
            for (int nt = 0; nt < 2; ++nt) {
                accY[m][nt] = (f32x4){0.f, 0.f, 0.f, 0.f};
                accG[m][nt] = (f32x4){0.f, 0.f, 0.f, 0.f};
            }

#pragma unroll
        for (int ks = 0; ks < 4; ++ks) {
#pragma unroll
            for (int m = 0; m < 4; ++m) {
                int arow = m * 16 + l16;
                bf16x8 a_h = *(const bf16x8*)(&sxh[arow * LDSP + ks * 32 + quad * 8]);
                bf16x8 a_l = *(const bf16x8*)(&sxl[arow * LDSP + ks * 32 + quad * 8]);
#pragma unroll
                for (int nt = 0; nt < 2; ++nt) {
                    // y = x . angle  (3-term split product)
                    accY[m][nt] = MFMA(a_h, wfa_h[nt][ks], accY[m][nt]);
                    accY[m][nt] = MFMA(a_h, wfa_l[nt][ks], accY[m][nt]);
                    accY[m][nt] = MFMA(a_l, wfa_h[nt][ks], accY[m][nt]);
                    // g = x . log|w|
                    accG[m][nt] = MFMA(a_h, wfg_h[nt][ks], accG[m][nt]);
                    accG[m][nt] = MFMA(a_h, wfg_l[nt][ks], accG[m][nt]);
                    accG[m][nt] = MFMA(a_l, wfg_h[nt][ks], accG[m][nt]);
                }
            }
        }

        // ---- epilogue: out = cos(y + bias) * exp(g) ----
#pragma unroll
        for (int m = 0; m < 4; ++m) {
            int rowb = R0 + m * 16 + quad * 4;
#pragma unroll
            for (int nt = 0; nt < 2; ++nt) {
                int o = n0 + nt * 16 + l16;
#pragma unroll
                for (int r = 0; r < 4; ++r) {
                    float y = accY[m][nt][r] + bias_v[nt];
                    float g = accG[m][nt][r];
                    out[(size_t)(rowb + r) * 128 + o] = __cosf(y) * __expf(g);
                }
            }
        }
    }
}

extern "C" void kernel_launch(void* const* d_in, const int* in_sizes, int n_in,
                              void* d_out, int out_size, void* d_ws, size_t ws_size,
                              hipStream_t stream) {
    const float* x    = (const float*)d_in[0];
    const float* wr   = (const float*)d_in[1];
    const float* wi   = (const float*)d_in[2];
    const float* bias = (const float*)d_in[3];
    float* out = (float*)d_out;
    unsigned short* wsplit = (unsigned short*)d_ws;   // needs 128 KiB

    ces_prep<<<64, 256, 0, stream>>>(wr, wi, wsplit);

    const int B = 262144;
    const int nchunks = B / BM;          // 4096
    ces_main<<<1024, 256, 0, stream>>>(x, wsplit, bias, out, nchunks);
}

// Round 2
// 298.270 us; speedup vs baseline: 1.0426x; 1.0426x over previous
//
#include <hip/hip_runtime.h>

// ---------------------------------------------------------------------------
// CESLayer: out[b,o] = cos(x@angle^T + bias) * exp(x@log|w|^T)
// B=262144, I=O=128. Memory floor ~38-42us (~240MB @ 6.3TB/s).
// R2: software-pipelined chunk loop — next chunk's x prefetched into registers
// during MFMA/epilogue of current chunk (vmcnt drain at the next barrier is
// where the data is needed). Interleaved Y/G MFMA chains, NT stores.
// ---------------------------------------------------------------------------

typedef __attribute__((ext_vector_type(8))) short bf16x8;   // 8 bf16 = 4 VGPRs
typedef __attribute__((ext_vector_type(4))) float f32x4;
typedef __attribute__((ext_vector_type(4))) unsigned short u16x4;

#define MFMA(a, b, c) __builtin_amdgcn_mfma_f32_16x16x32_bf16((a), (b), (c), 0, 0, 0)

__device__ __forceinline__ unsigned short f2bf_rne(float f) {
    unsigned u = __float_as_uint(f);
    unsigned r = u + 0x7FFFu + ((u >> 16) & 1u);
    return (unsigned short)(r >> 16);
}

// Split fp32 -> bf16 hi (truncated) + bf16 lo (RNE of exact residual).
// hi = f & 0xFFFF0000 makes the residual exactly representable; dropped
// xl*wl term ~2^-16 rel per element -> negligible vs 0.5575 threshold.
__device__ __forceinline__ void bf16_split(float f, unsigned short& hi, unsigned short& lo) {
    unsigned uh = __float_as_uint(f) & 0xFFFF0000u;
    hi = (unsigned short)(uh >> 16);
    lo = f2bf_rne(f - __uint_as_float(uh));
}

// ---------------------------------------------------------------------------
// Prep: angle=atan2(wi,wr), logmag=0.5*log(wr^2+wi^2), bf16 hi/lo split.
// ws layout (ushort): [0:16K) ang_hi [16K:32K) ang_lo [32K:48K) lg_hi [48K:64K) lg_lo
// ---------------------------------------------------------------------------
__global__ void ces_prep(const float* __restrict__ wr, const float* __restrict__ wi,
                         unsigned short* __restrict__ wsplit) {
    int idx = blockIdx.x * 256 + threadIdx.x;   // 0..16383
    float a = wr[idx], b = wi[idx];
    float r2 = a * a + b * b;
    float ang = atan2f(b, a);
    float lg = 0.5f * logf(r2);
    unsigned short ah, al, gh, gl;
    bf16_split(ang, ah, al);
    bf16_split(lg, gh, gl);
    wsplit[idx]         = ah;
    wsplit[16384 + idx] = al;
    wsplit[32768 + idx] = gh;
    wsplit[49152 + idx] = gl;
}

#define BM   64
#define LDSP 136   // 272B row stride -> 4-bank rotation, 2-way max (free)

__global__ __launch_bounds__(256, 2) void ces_main(
        const float* __restrict__ x,
        const unsigned short* __restrict__ wsplit,
        const float* __restrict__ bias,
        float* __restrict__ out,
        int nchunks) {
    __shared__ unsigned short sxh[BM * LDSP];
    __shared__ unsigned short sxl[BM * LDSP];

    const int tid  = threadIdx.x;
    const int wave = tid >> 6;
    const int lane = tid & 63;
    const int quad = lane >> 4;
    const int l16  = lane & 15;
    const int n0   = wave * 32;

    // ---- weight fragments into registers (once per block): 128 VGPRs ----
    bf16x8 wfa_h[2][4], wfa_l[2][4], wfg_h[2][4], wfg_l[2][4];
#pragma unroll
    for (int nt = 0; nt < 2; ++nt) {
        int o = n0 + nt * 16 + l16;
#pragma unroll
        for (int ks = 0; ks < 4; ++ks) {
            int off = o * 128 + ks * 32 + quad * 8;
            wfa_h[nt][ks] = *(const bf16x8*)(wsplit + off);
            wfa_l[nt][ks] = *(const bf16x8*)(wsplit + 16384 + off);
            wfg_h[nt][ks] = *(const bf16x8*)(wsplit + 32768 + off);
            wfg_l[nt][ks] = *(const bf16x8*)(wsplit + 49152 + off);
        }
    }
    float bias_v[2];
    bias_v[0] = bias[n0 + l16];
    bias_v[1] = bias[n0 + 16 + l16];

    // per-thread staging coordinates (float4 granularity)
    const int srow[8] = { (tid + 0*256) >> 5, (tid + 1*256) >> 5, (tid + 2*256) >> 5,
                          (tid + 3*256) >> 5, (tid + 4*256) >> 5, (tid + 5*256) >> 5,
                          (tid + 6*256) >> 5, (tid + 7*256) >> 5 };
    const int sc4 = (tid & 31) * 4;

    // ---- prologue: prefetch chunk 0 into registers ----
    float4 pf[8];
    {
        const float* xp = x + (size_t)blockIdx.x * BM * 128;
#pragma unroll
        for (int it = 0; it < 8; ++it)
            pf[it] = *(const float4*)(xp + srow[it] * 128 + sc4);
    }

    for (int chunk = blockIdx.x; chunk < nchunks; chunk += gridDim.x) {
        // barrier A: previous chunk's LDS readers done; vmcnt drain = pf ready
        __syncthreads();

        // ---- convert prefetched registers -> LDS bf16 hi/lo ----
#pragma unroll
        for (int it = 0; it < 8; ++it) {
            u16x4 hv, lv;
            bf16_split(pf[it].x, ((unsigned short*)&hv)[0], ((unsigned short*)&lv)[0]);
            bf16_split(pf[it].y, ((unsigned short*)&hv)[1], ((unsigned short*)&lv)[1]);
            bf16_split(pf[it].z, ((unsigned short*)&hv)[2], ((unsigned short*)&lv)[2]);
            bf16_split(pf[it].w, ((unsigned short*)&hv)[3], ((unsigned short*)&lv)[3]);
            *(u16x4*)(&sxh[srow[it] * LDSP + sc4]) = hv;
            *(u16x4*)(&sxl[srow[it] * LDSP + sc4]) = lv;
        }
        __syncthreads();   // barrier B: LDS tile visible to all waves

        // ---- issue prefetch for next chunk; stays in flight across MFMA ----
        int nxt = chunk + gridDim.x;
        if (nxt < nchunks) {
            const float* xp = x + (size_t)nxt * BM * 128;
#pragma unroll
            for (int it = 0; it < 8; ++it)
                pf[it] = *(const float4*)(xp + srow[it] * 128 + sc4);
        }

        // ---- MFMA: 4 m-tiles x 2 n-tiles, K=128 in 4 steps of 32 ----
        f32x4 accY[4][2], accG[4][2];
#pragma unroll
        for (int m = 0; m < 4; ++m)
#pragma unroll
            for (int nt = 0; nt < 2; ++nt) {
                accY[m][nt] = (f32x4){0.f, 0.f, 0.f, 0.f};
                accG[m][nt] = (f32x4){0.f, 0.f, 0.f, 0.f};
            }

#pragma unroll
        for (int ks = 0; ks < 4; ++ks) {
#pragma unroll
            for (int m = 0; m < 4; ++m) {
                int ao = (m * 16 + l16) * LDSP + ks * 32 + quad * 8;
                bf16x8 a_h = *(const bf16x8*)(&sxh[ao]);
                bf16x8 a_l = *(const bf16x8*)(&sxl[ao]);
                // 12 MFMAs, interleaved across 4 independent accumulators
                accY[m][0] = MFMA(a_h, wfa_h[0][ks], accY[m][0]);
                accG[m][0] = MFMA(a_h, wfg_h[0][ks], accG[m][0]);
                accY[m][1] = MFMA(a_h, wfa_h[1][ks], accY[m][1]);
                accG[m][1] = MFMA(a_h, wfg_h[1][ks], accG[m][1]);
                accY[m][0] = MFMA(a_h, wfa_l[0][ks], accY[m][0]);
                accG[m][0] = MFMA(a_h, wfg_l[0][ks], accG[m][0]);
                accY[m][1] = MFMA(a_h, wfa_l[1][ks], accY[m][1]);
                accG[m][1] = MFMA(a_h, wfg_l[1][ks], accG[m][1]);
                accY[m][0] = MFMA(a_l, wfa_h[0][ks], accY[m][0]);
                accG[m][0] = MFMA(a_l, wfg_h[0][ks], accG[m][0]);
                accY[m][1] = MFMA(a_l, wfa_h[1][ks], accY[m][1]);
                accG[m][1] = MFMA(a_l, wfg_h[1][ks], accG[m][1]);
            }
        }

        // ---- epilogue: out = cos(y + bias) * exp(g), nontemporal ----
        const int R0 = chunk * BM;
#pragma unroll
        for (int m = 0; m < 4; ++m) {
            int rowb = R0 + m * 16 + quad * 4;
#pragma unroll
            for (int nt = 0; nt < 2; ++nt) {
                int o = n0 + nt * 16 + l16;
#pragma unroll
                for (int r = 0; r < 4; ++r) {
                    float y = accY[m][nt][r] + bias_v[nt];
                    float g = accG[m][nt][r];
                    __builtin_nontemporal_store(__cosf(y) * __expf(g),
                                                out + (size_t)(rowb + r) * 128 + o);
                }
            }
        }
    }
}

extern "C" void kernel_launch(void* const* d_in, const int* in_sizes, int n_in,
                              void* d_out, int out_size, void* d_ws, size_t ws_size,
                              hipStream_t stream) {
    const float* x    = (const float*)d_in[0];
    const float* wr   = (const float*)d_in[1];
    const float* wi   = (const float*)d_in[2];
    const float* bias = (const float*)d_in[3];
    float* out = (float*)d_out;
    unsigned short* wsplit = (unsigned short*)d_ws;   // 128 KiB

    ces_prep<<<64, 256, 0, stream>>>(wr, wi, wsplit);

    const int B = 262144;
    const int nchunks = B / BM;          // 4096
    ces_main<<<1024, 256, 0, stream>>>(x, wsplit, bias, out, nchunks);
}

// Round 3
// 284.141 us; speedup vs baseline: 1.0944x; 1.0497x over previous
//
#include <hip/hip_runtime.h>

// ---------------------------------------------------------------------------
// CESLayer: out[b,o] = cos(x@angle^T + bias) * exp(x@log|w|^T)
// B=262144, I=O=128. Memory floor ~38-42us (~240-270MB @ 6.3TB/s).
// R3: barrier-free, LDS-free. Each wave is an independent pipeline:
//   - owns 32 O-cols, weight fragments resident in registers (128 VGPR)
//   - grid-strides over 16-row x tiles, loading DIRECTLY into MFMA A-fragment
//     layout (lane reads x[l16][quad*8+ks*32 .. +8] as 2 float4 per ks)
//   - fp32->bf16 hi/lo split in VALU, 12 MFMAs per ks (3-term split product)
//   - fused cos/exp epilogue, plain (L2-assembled) stores — NT removed, it
//     caused 1.9x write amplification (partial 64B lines to HBM) in R2.
// Prefetch depth 1 tile/wave keeps ~8KB/wave in flight; 8 desync'd waves/CU
// give ~30KB avg outstanding vs ~9KB needed for 6 TB/s.
// ---------------------------------------------------------------------------

typedef __attribute__((ext_vector_type(8))) short bf16x8;   // 8 bf16 = 4 VGPRs
typedef __attribute__((ext_vector_type(4))) float f32x4;

#define MFMA(a, b, c) __builtin_amdgcn_mfma_f32_16x16x32_bf16((a), (b), (c), 0, 0, 0)

__device__ __forceinline__ unsigned short f2bf_rne(float f) {
    unsigned u = __float_as_uint(f);
    unsigned r = u + 0x7FFFu + ((u >> 16) & 1u);
    return (unsigned short)(r >> 16);
}

// Split fp32 -> bf16 hi (truncated) + bf16 lo (RNE of exact residual).
__device__ __forceinline__ void bf16_split(float f, unsigned short& hi, unsigned short& lo) {
    unsigned uh = __float_as_uint(f) & 0xFFFF0000u;
    hi = (unsigned short)(uh >> 16);
    lo = f2bf_rne(f - __uint_as_float(uh));
}

// Pack two floats into one dword of bf16-hi (low=f0) and one of bf16-lo.
__device__ __forceinline__ void cvt_pair(float f0, float f1, unsigned& h, unsigned& l) {
    unsigned u0 = __float_as_uint(f0), u1 = __float_as_uint(f1);
    unsigned uh0 = u0 & 0xFFFF0000u, uh1 = u1 & 0xFFFF0000u;
    h = (uh0 >> 16) | uh1;
    float r0 = f0 - __uint_as_float(uh0);
    float r1 = f1 - __uint_as_float(uh1);
    unsigned v0 = __float_as_uint(r0), v1 = __float_as_uint(r1);
    v0 = v0 + 0x7FFFu + ((v0 >> 16) & 1u);
    v1 = v1 + 0x7FFFu + ((v1 >> 16) & 1u);
    l = (v0 >> 16) | (v1 & 0xFFFF0000u);
}

// ---------------------------------------------------------------------------
// Prep: angle=atan2(wi,wr), logmag=0.5*log(wr^2+wi^2), bf16 hi/lo split.
// ws layout (ushort): [0:16K) ang_hi [16K:32K) ang_lo [32K:48K) lg_hi [48K:64K) lg_lo
// ---------------------------------------------------------------------------
__global__ void ces_prep(const float* __restrict__ wr, const float* __restrict__ wi,
                         unsigned short* __restrict__ wsplit) {
    int idx = blockIdx.x * 256 + threadIdx.x;   // 0..16383
    float a = wr[idx], b = wi[idx];
    float r2 = a * a + b * b;
    float ang = atan2f(b, a);
    float lg = 0.5f * logf(r2);
    unsigned short ah, al, gh, gl;
    bf16_split(ang, ah, al);
    bf16_split(lg, gh, gl);
    wsplit[idx]         = ah;
    wsplit[16384 + idx] = al;
    wsplit[32768 + idx] = gh;
    wsplit[49152 + idx] = gl;
}

// ---------------------------------------------------------------------------
// Main. 256 threads = 4 independent waves; wave w owns O-cols [32w, 32w+32).
// MFMA 16x16x32 bf16 layouts (verified R1/R2): A: m=lane&15, k=quad*8+j;
// B: n=lane&15, k=quad*8+j; C/D: col=lane&15, row=quad*4+reg.
// ---------------------------------------------------------------------------
__global__ __launch_bounds__(256, 2) void ces_main(
        const float* __restrict__ x,
        const unsigned short* __restrict__ wsplit,
        const float* __restrict__ bias,
        float* __restrict__ out,
        int ntiles) {
    const int tid  = threadIdx.x;
    const int wave = tid >> 6;
    const int lane = tid & 63;
    const int quad = lane >> 4;
    const int l16  = lane & 15;
    const int n0   = wave * 32;

    // ---- weight fragments into registers (once per block): 128 regs ----
    bf16x8 wfa_h[2][4], wfa_l[2][4], wfg_h[2][4], wfg_l[2][4];
#pragma unroll
    for (int nt = 0; nt < 2; ++nt) {
        int o = n0 + nt * 16 + l16;
#pragma unroll
        for (int ks = 0; ks < 4; ++ks) {
            int off = o * 128 + ks * 32 + quad * 8;
            wfa_h[nt][ks] = *(const bf16x8*)(wsplit + off);
            wfa_l[nt][ks] = *(const bf16x8*)(wsplit + 16384 + off);
            wfg_h[nt][ks] = *(const bf16x8*)(wsplit + 32768 + off);
            wfg_l[nt][ks] = *(const bf16x8*)(wsplit + 49152 + off);
        }
    }
    float bias_v[2];
    bias_v[0] = bias[n0 + l16];
    bias_v[1] = bias[n0 + 16 + l16];

    // lane's float offset within a 16x128 tile, fragment layout
    const int lo0 = l16 * 128 + quad * 8;

    // ---- prologue: prefetch tile blockIdx.x ----
    float4 pf[8];
    {
        const float* xp = x + (size_t)blockIdx.x * (16 * 128);
#pragma unroll
        for (int ks = 0; ks < 4; ++ks) {
            pf[2 * ks]     = *(const float4*)(xp + lo0 + ks * 32);
            pf[2 * ks + 1] = *(const float4*)(xp + lo0 + ks * 32 + 4);
        }
    }

    for (int t = blockIdx.x; t < ntiles; t += gridDim.x) {
        // ---- convert prefetched tile to bf16 hi/lo fragments ----
        union { unsigned u[4]; bf16x8 v; } ah[4], al[4];
#pragma unroll
        for (int ks = 0; ks < 4; ++ks) {
            cvt_pair(pf[2*ks].x,   pf[2*ks].y,   ah[ks].u[0], al[ks].u[0]);
            cvt_pair(pf[2*ks].z,   pf[2*ks].w,   ah[ks].u[1], al[ks].u[1]);
            cvt_pair(pf[2*ks+1].x, pf[2*ks+1].y, ah[ks].u[2], al[ks].u[2]);
            cvt_pair(pf[2*ks+1].z, pf[2*ks+1].w, ah[ks].u[3], al[ks].u[3]);
        }

        // ---- issue prefetch for next tile; in flight across MFMA/epilogue ----
        int tn = t + gridDim.x;
        if (tn < ntiles) {
            const float* xp = x + (size_t)tn * (16 * 128);
#pragma unroll
            for (int ks = 0; ks < 4; ++ks) {
                pf[2 * ks]     = *(const float4*)(xp + lo0 + ks * 32);
                pf[2 * ks + 1] = *(const float4*)(xp + lo0 + ks * 32 + 4);
            }
        }

        // ---- MFMA: K=128 in 4 steps, 12 MFMAs each (3-term hi/lo) ----
        f32x4 accY[2], accG[2];
        accY[0] = (f32x4){0.f, 0.f, 0.f, 0.f};
        accY[1] = (f32x4){0.f, 0.f, 0.f, 0.f};
        accG[0] = (f32x4){0.f, 0.f, 0.f, 0.f};
        accG[1] = (f32x4){0.f, 0.f, 0.f, 0.f};
#pragma unroll
        for (int ks = 0; ks < 4; ++ks) {
            bf16x8 a_h = ah[ks].v;
            bf16x8 a_l = al[ks].v;
            accY[0] = MFMA(a_h, wfa_h[0][ks], accY[0]);
            accG[0] = MFMA(a_h, wfg_h[0][ks], accG[0]);
            accY[1] = MFMA(a_h, wfa_h[1][ks], accY[1]);
            accG[1] = MFMA(a_h, wfg_h[1][ks], accG[1]);
            accY[0] = MFMA(a_h, wfa_l[0][ks], accY[0]);
            accG[0] = MFMA(a_h, wfg_l[0][ks], accG[0]);
            accY[1] = MFMA(a_h, wfa_l[1][ks], accY[1]);
            accG[1] = MFMA(a_h, wfg_l[1][ks], accG[1]);
            accY[0] = MFMA(a_l, wfa_h[0][ks], accY[0]);
            accG[0] = MFMA(a_l, wfg_h[0][ks], accG[0]);
            accY[1] = MFMA(a_l, wfa_h[1][ks], accY[1]);
            accG[1] = MFMA(a_l, wfg_h[1][ks], accG[1]);
        }

        // ---- epilogue: out = cos(y + bias) * exp(g), plain stores ----
        const int R0 = t * 16;
#pragma unroll
        for (int nt = 0; nt < 2; ++nt) {
            int o = n0 + nt * 16 + l16;
#pragma unroll
            for (int r = 0; r < 4; ++r) {
                float y = accY[nt][r] + bias_v[nt];
                float g = accG[nt][r];
                out[(size_t)(R0 + quad * 4 + r) * 128 + o] = __cosf(y) * __expf(g);
            }
        }
    }
}

extern "C" void kernel_launch(void* const* d_in, const int* in_sizes, int n_in,
                              void* d_out, int out_size, void* d_ws, size_t ws_size,
                              hipStream_t stream) {
    const float* x    = (const float*)d_in[0];
    const float* wr   = (const float*)d_in[1];
    const float* wi   = (const float*)d_in[2];
    const float* bias = (const float*)d_in[3];
    float* out = (float*)d_out;
    unsigned short* wsplit = (unsigned short*)d_ws;   // 128 KiB

    ces_prep<<<64, 256, 0, stream>>>(wr, wi, wsplit);

    const int B = 262144;
    const int ntiles = B / 16;           // 16384 tiles of 16 rows
    ces_main<<<2048, 256, 0, stream>>>(x, wsplit, bias, out, ntiles);
}